// Round 12
// baseline (168.224 us; speedup 1.0000x reference)
//
#include <hip/hip_runtime.h>
#include <hip/hip_bf16.h>

#define NN 10000
#define NE 320000
#define FDIM 128
#define NRBF 20
#define PHI_DIM 384
#define NKEY NN
#define SCAN_BLOCKS 40  // 40*256 = 10240 >= NKEY+1

typedef unsigned int uint;
typedef unsigned short ushort;

#if __has_builtin(__builtin_amdgcn_fdot2_f32_bf16)
#define USE_DOT2 1
typedef __bf16 bf16x2 __attribute__((ext_vector_type(2)));
#else
#define USE_DOT2 0
#endif

__device__ __forceinline__ ushort f2bf(float x) {
  __hip_bfloat16 b = __float2bfloat16(x);
  return *(ushort*)&b;
}

// Interleaved per-node table row (1280 B), 3 gathers per edge:
//   [0,512)     uint  : wy_bf16<<16 | wx_bf16     (w* = vf*·phi0, precomputed)
//   [512,1024)  uint  : phi1_bf16<<16 | wz_bf16
//   [1024,1280) ushort: phi2_bf16

// ---------------- node MLP + fused edge-count + fused w-plane pack ----------------
__global__ void phi_kernel(const float* __restrict__ S, const float* __restrict__ W1,
                           const float* __restrict__ b1, const float* __restrict__ W2,
                           const float* __restrict__ b2, const float* __restrict__ vf,
                           const int* __restrict__ idx_i, int* __restrict__ counts,
                           char* __restrict__ tab) {
  __shared__ float s_s[8][FDIM];
  __shared__ float h_s[8][FDIM];
  const int t = threadIdx.x;
  const int n0 = blockIdx.x * 8;
  // fused: edge counting (exactly 2 edges per thread, 1250*128*2 == NE)
  {
    const int e0 = (blockIdx.x * 128 + t) * 2;
    atomicAdd(&counts[idx_i[e0]], 1);
    atomicAdd(&counts[idx_i[e0 + 1]], 1);
  }
#pragma unroll
  for (int n = 0; n < 8; n++) s_s[n][t] = S[(n0 + n) * FDIM + t];
  __syncthreads();
  float acc[8];
#pragma unroll
  for (int n = 0; n < 8; n++) acc[n] = 0.f;
  for (int k = 0; k < FDIM; k++) {
    float w = W1[k * FDIM + t];
#pragma unroll
    for (int n = 0; n < 8; n++) acc[n] += s_s[n][k] * w;
  }
  float bb = b1[t];
#pragma unroll
  for (int n = 0; n < 8; n++) {
    float x = acc[n] + bb;
    h_s[n][t] = x / (1.0f + expf(-x));
  }
  __syncthreads();
  float a0[8], a1[8], a2[8];
#pragma unroll
  for (int n = 0; n < 8; n++) { a0[n] = 0.f; a1[n] = 0.f; a2[n] = 0.f; }
  for (int k = 0; k < FDIM; k++) {
    float w0 = W2[k * PHI_DIM + t];
    float w1 = W2[k * PHI_DIM + t + 128];
    float w2 = W2[k * PHI_DIM + t + 256];
#pragma unroll
    for (int n = 0; n < 8; n++) {
      float hv = h_s[n][k];
      a0[n] += hv * w0;
      a1[n] += hv * w1;
      a2[n] += hv * w2;
    }
  }
  float c0 = b2[t], c1 = b2[t + 128], c2 = b2[t + 256];
#pragma unroll
  for (int n = 0; n < 8; n++) {
    const int node = n0 + n;
    const float p0 = a0[n] + c0;
    const float p1 = a1[n] + c1;
    const float p2 = a2[n] + c2;
    const float* src = vf + (size_t)node * (FDIM * 3) + t * 3;
    const uint wx = f2bf(src[0] * p0);
    const uint wy = f2bf(src[1] * p0);
    const uint wz = f2bf(src[2] * p0);
    char* pb = tab + (size_t)node * 1280;
    ((uint*)pb)[t] = (wy << 16) | wx;
    ((uint*)(pb + 512))[t] = ((uint)f2bf(p1) << 16) | wz;
    ((ushort*)(pb + 1024))[t] = f2bf(p2);
  }
}

// ---------------- hierarchical scan: block scan -> sum scan -> add base ----------------
__global__ void scan1_kernel(const int* __restrict__ counts, int* __restrict__ offsets,
                             int* __restrict__ blocksums) {
  __shared__ int s[256];
  const int t = threadIdx.x;
  const int idx = blockIdx.x * 256 + t;
  const int c = counts[idx];  // region zero-padded to 10240
  s[t] = c;
  __syncthreads();
  for (int off = 1; off < 256; off <<= 1) {
    int v = (t >= off) ? s[t - off] : 0;
    __syncthreads();
    s[t] += v;
    __syncthreads();
  }
  if (idx < NKEY) offsets[idx] = s[t] - c;
  if (t == 255) blocksums[blockIdx.x] = s[255];
}

__global__ void scan2_kernel(int* __restrict__ blocksums, int* __restrict__ offsets) {
  __shared__ int s[64];
  const int t = threadIdx.x;  // 64 threads
  int v0 = (t < SCAN_BLOCKS) ? blocksums[t] : 0;
  s[t] = v0;
  __syncthreads();
  for (int off = 1; off < 64; off <<= 1) {
    int v = (t >= off) ? s[t - off] : 0;
    __syncthreads();
    s[t] += v;
    __syncthreads();
  }
  if (t < SCAN_BLOCKS) blocksums[t] = s[t] - v0;   // exclusive base per block
  if (t == SCAN_BLOCKS - 1) offsets[NKEY] = s[t];  // total = NE
}

__global__ void scan3_kernel(int* __restrict__ offsets, const int* __restrict__ blocksums) {
  const int idx = blockIdx.x * 256 + threadIdx.x;
  if (idx < NKEY) offsets[idx] += blocksums[blockIdx.x];  // must NOT touch offsets[NKEY]
}

// stage CSR-ordered: jlist (4 B) + 64-B records {j, cut, dx, dy, dz, pad, (rbf*cut)[20] bf16}
// slot claim via atomicSub on counts (scan already consumed counts; ends at 0)
__global__ void stage_kernel(const int* __restrict__ idx_i, const int* __restrict__ idx_j,
                             const float* __restrict__ cut, const float* __restrict__ dir,
                             const float* __restrict__ rbf, const int* __restrict__ offsets,
                             int* __restrict__ counts, uint* __restrict__ edata,
                             int* __restrict__ jlist) {
  int e = blockIdx.x * blockDim.x + threadIdx.x;
  if (e >= NE) return;
  int i = idx_i[e];
  int pos = atomicSub(&counts[i], 1) - 1;
  const int slot = offsets[i] + pos;
  const int j = idx_j[e];
  jlist[slot] = j;
  uint* d = edata + (size_t)slot * 16;
  const float c = cut[e];
  d[0] = (uint)j;
  d[1] = __float_as_uint(c);
  d[2] = __float_as_uint(dir[e * 3 + 0]);
  d[3] = __float_as_uint(dir[e * 3 + 1]);
  d[4] = __float_as_uint(dir[e * 3 + 2]);
  d[5] = 0u;
  const float* rb = rbf + (size_t)e * NRBF;
#pragma unroll
  for (int r = 0; r < 10; r++) {
    uint lo = (uint)f2bf(rb[2 * r] * c);
    uint hi = (uint)f2bf(rb[2 * r + 1] * c);
    d[6 + r] = (hi << 16) | lo;
  }
}

// ---------------- node-centric accumulation: 1 node / 128-thread block, 2-edge pipeline ----
__global__ __launch_bounds__(128, 5) void node_kernel(
    const uint* __restrict__ edata, const int* __restrict__ jlist,
    const float* __restrict__ Wr, const float* __restrict__ br,
    const char* __restrict__ tab, const float* __restrict__ sf,
    const float* __restrict__ vf, const int* __restrict__ offsets,
    float* __restrict__ out) {
  const int f = threadIdx.x;  // 0..127
#if USE_DOT2
  bf16x2 wrA[10], wrB[10], wrC[10];
#pragma unroll
  for (int r = 0; r < 10; r++) {
    uint a = ((uint)f2bf(Wr[(2 * r + 1) * PHI_DIM + f]) << 16) | f2bf(Wr[(2 * r) * PHI_DIM + f]);
    uint b = ((uint)f2bf(Wr[(2 * r + 1) * PHI_DIM + f + 128]) << 16) |
             f2bf(Wr[(2 * r) * PHI_DIM + f + 128]);
    uint c = ((uint)f2bf(Wr[(2 * r + 1) * PHI_DIM + f + 256]) << 16) |
             f2bf(Wr[(2 * r) * PHI_DIM + f + 256]);
    wrA[r] = __builtin_bit_cast(bf16x2, a);
    wrB[r] = __builtin_bit_cast(bf16x2, b);
    wrC[r] = __builtin_bit_cast(bf16x2, c);
  }
#else
  float wrA[NRBF], wrB[NRBF], wrC[NRBF];
#pragma unroll
  for (int r = 0; r < NRBF; r++) {
    wrA[r] = Wr[r * PHI_DIM + f];
    wrB[r] = Wr[r * PHI_DIM + f + 128];
    wrC[r] = Wr[r * PHI_DIM + f + 256];
  }
#endif
  const int n = blockIdx.x;
  const int beg = offsets[n], end = offsets[n + 1];
  const float br0 = br[f], br1 = br[f + 128], br2 = br[f + 256];
  float ss = 0.f, ax = 0.f, ay = 0.f, az = 0.f;
  const int f4 = f * 4;

  auto process = [&](const uint4* rec, uint d0, uint d1, uint zu) {
    uint4 q0 = rec[0];
    uint4 q1 = rec[1];
    uint4 q2 = rec[2];
    uint4 q3 = rec[3];
    const float c = __uint_as_float(q0.y);
    const float dx = __uint_as_float(q0.z);
    const float dy = __uint_as_float(q0.w);
    const float dz = __uint_as_float(q1.x);
    uint rbp[10] = {q1.z, q1.w, q2.x, q2.y, q2.z, q2.w, q3.x, q3.y, q3.z, q3.w};
    float g0 = 0.f, g1 = 0.f, g2 = 0.f;  // rbf pre-scaled by cut
#if USE_DOT2
#pragma unroll
    for (int r = 0; r < 10; r++) {
      bf16x2 rp = __builtin_bit_cast(bf16x2, rbp[r]);
      g0 = __builtin_amdgcn_fdot2_f32_bf16(rp, wrA[r], g0, false);
      g1 = __builtin_amdgcn_fdot2_f32_bf16(rp, wrB[r], g1, false);
      g2 = __builtin_amdgcn_fdot2_f32_bf16(rp, wrC[r], g2, false);
    }
#else
#pragma unroll
    for (int r = 0; r < 10; r++) {
      float rlo = __uint_as_float(rbp[r] << 16);
      float rhi = __uint_as_float(rbp[r] & 0xffff0000u);
      g0 += rlo * wrA[2 * r] + rhi * wrA[2 * r + 1];
      g1 += rlo * wrB[2 * r] + rhi * wrB[2 * r + 1];
      g2 += rlo * wrC[2 * r] + rhi * wrC[2 * r + 1];
    }
#endif
    g0 += br0 * c;
    g1 += br1 * c;
    g2 += br2 * c;
    const float wx = __uint_as_float(d0 << 16);
    const float wy = __uint_as_float(d0 & 0xffff0000u);
    const float wz = __uint_as_float(d1 << 16);
    const float p1 = __uint_as_float(d1 & 0xffff0000u);
    const float p2 = __uint_as_float(zu << 16);
    const float vs = p2 * g2;
    ss += p1 * g1;
    ax += wx * g0 + vs * dx;
    ay += wy * g0 + vs * dy;
    az += wz * g0 + vs * dz;
  };

  int p = beg;
  for (; p + 2 <= end; p += 2) {
    const int j0 = jlist[p];
    const int j1 = jlist[p + 1];
    const char* B0 = tab + (size_t)j0 * 1280;
    const char* B1 = tab + (size_t)j1 * 1280;
    const uint d00 = *(const uint*)(B0 + f4);
    const uint d01 = *(const uint*)(B0 + 512 + f4);
    const uint z0 = *(const ushort*)(B0 + 1024 + f * 2);
    const uint d10 = *(const uint*)(B1 + f4);
    const uint d11 = *(const uint*)(B1 + 512 + f4);
    const uint z1 = *(const ushort*)(B1 + 1024 + f * 2);
    const uint4* r0 = (const uint4*)(edata + (size_t)p * 16);
    const uint4* r1 = (const uint4*)(edata + (size_t)(p + 1) * 16);
    process(r0, d00, d01, z0);
    process(r1, d10, d11, z1);
  }
  if (p < end) {
    const int j0 = jlist[p];
    const char* B0 = tab + (size_t)j0 * 1280;
    const uint d00 = *(const uint*)(B0 + f4);
    const uint d01 = *(const uint*)(B0 + 512 + f4);
    const uint z0 = *(const ushort*)(B0 + 1024 + f * 2);
    process((const uint4*)(edata + (size_t)p * 16), d00, d01, z0);
  }

  const float inv = 1.0f / (float)(end - beg);
  out[(size_t)n * FDIM + f] = sf[(size_t)n * FDIM + f] + ss * inv;
  float* ov = out + (size_t)NN * FDIM + (size_t)n * (FDIM * 3) + f * 3;
  const float* iv = vf + (size_t)n * (FDIM * 3) + f * 3;
  ov[0] = iv[0] + ax * inv;
  ov[1] = iv[1] + ay * inv;
  ov[2] = iv[2] + az * inv;
}

extern "C" void kernel_launch(void* const* d_in, const int* in_sizes, int n_in,
                              void* d_out, int out_size, void* d_ws, size_t ws_size,
                              hipStream_t stream) {
  const int* idx_i = (const int*)d_in[0];
  const int* idx_j = (const int*)d_in[1];
  const float* rel_dir = (const float*)d_in[2];
  const float* cut = (const float*)d_in[3];
  const float* rbf = (const float*)d_in[4];
  const float* sf = (const float*)d_in[5];
  const float* vf = (const float*)d_in[6];
  const float* W1 = (const float*)d_in[7];
  const float* b1 = (const float*)d_in[8];
  const float* W2 = (const float*)d_in[9];
  const float* b2 = (const float*)d_in[10];
  const float* Wr = (const float*)d_in[11];
  const float* br = (const float*)d_in[12];
  float* out = (float*)d_out;

  // workspace layout (bytes):
  //   counts   : [0, 40960)            10240 ints (zero-padded; consumed by stage)
  //   offsets  : [40960, 81920)        10001 ints
  //   blocksums: [81920, 82176)        64 ints
  //   edata    : [90112, 20570112)     320000 * 64 B
  //   tab      : [20570112, 33370112)  10000 * 1280 B interleaved w/phi planes
  //   jlist    : [33370112, 34650112)  320000 ints
  char* w = (char*)d_ws;
  int* counts = (int*)w;
  int* offsets = (int*)(w + 40960);
  int* blocksums = (int*)(w + 81920);
  uint* edata = (uint*)(w + 90112);
  char* tab = w + 20570112;
  int* jlist = (int*)(w + 33370112);

  hipMemsetAsync(w, 0, 40960, stream);  // zero counts only
  hipLaunchKernelGGL(phi_kernel, dim3(NN / 8), dim3(128), 0, stream, sf, W1, b1, W2, b2, vf,
                     idx_i, counts, tab);
  hipLaunchKernelGGL(scan1_kernel, dim3(SCAN_BLOCKS), dim3(256), 0, stream, counts, offsets,
                     blocksums);
  hipLaunchKernelGGL(scan2_kernel, dim3(1), dim3(64), 0, stream, blocksums, offsets);
  hipLaunchKernelGGL(scan3_kernel, dim3(SCAN_BLOCKS), dim3(256), 0, stream, offsets, blocksums);
  hipLaunchKernelGGL(stage_kernel, dim3((NE + 255) / 256), dim3(256), 0, stream, idx_i, idx_j,
                     cut, rel_dir, rbf, offsets, counts, edata, jlist);
  hipLaunchKernelGGL(node_kernel, dim3(NN), dim3(128), 0, stream, edata, jlist, Wr, br, tab, sf,
                     vf, offsets, out);
}